// Round 12
// baseline (200.927 us; speedup 1.0000x reference)
//
#include <hip/hip_runtime.h>
#include <hip/hip_bf16.h>
#include <math.h>

// Problem constants
#define S_LEN   2048
#define BATCH   2
#define DMODEL  1024
#define NHEADS  16
#define DKH     64
#define MROWS   (BATCH * S_LEN)   // 4096

typedef __attribute__((ext_vector_type(8))) __bf16 bf16x8;
typedef __attribute__((ext_vector_type(4))) float f32x4;
typedef __attribute__((ext_vector_type(8))) unsigned short u16x8;

__device__ __forceinline__ float bfu2f(unsigned short u) {
    union { unsigned int i; float f; } v;
    v.i = ((unsigned int)u) << 16;
    return v.f;
}

__device__ __forceinline__ unsigned short f2bfu(float f) {
    union { __bf16 h; unsigned short u; } v;
    v.h = (__bf16)f;    // native RNE cvt
    return v.u;
}

#define LGKM0() __builtin_amdgcn_s_waitcnt(0xc07f)   // lgkmcnt(0), vmcnt free

// ---------------------------------------------------------------------------
// Weight pre-convert: Wq/Wk/Wv fp32 -> bf16 into ws[24MB..30MB). That region
// is later overwritten by A (attn output) -- safe, QKV completes first.
// ---------------------------------------------------------------------------
__global__ __launch_bounds__(256) void cvt_w(
    const float* __restrict__ W0, const float* __restrict__ W1, const float* __restrict__ W2,
    unsigned short* __restrict__ Wb)   // [3][1024*1024] bf16
{
    const float* W = (blockIdx.y == 0) ? W0 : (blockIdx.y == 1) ? W1 : W2;
    size_t idx = ((size_t)blockIdx.x * 256 + threadIdx.x) * 8;
    float4 a = *(const float4*)(W + idx);
    float4 b = *(const float4*)(W + idx + 4);
    u16x8 h;
    h[0] = f2bfu(a.x); h[1] = f2bfu(a.y); h[2] = f2bfu(a.z); h[3] = f2bfu(a.w);
    h[4] = f2bfu(b.x); h[5] = f2bfu(b.y); h[6] = f2bfu(b.z); h[7] = f2bfu(b.w);
    *(u16x8*)(Wb + (size_t)blockIdx.y * (DMODEL * DMODEL) + idx) = h;
}

// ---------------------------------------------------------------------------
// QKV MFMA GEMM R12: BK=64 -> 32 MFMAs per barrier pair (AITER density) at the
// SAME 36.9KB LDS (bf16 tiles; dodges the BK-128 occupancy trap). B operand is
// pre-converted bf16 (pure 16B copy staging). Loads stay inside the staging
// phase (R10 lesson: cross-phase reg prefetch regressed).
// LDS row stride 72 halves: frag-read lanes land 2-way on banks (free, m136).
// Epilogues: LDS round-trip, full-line stores (R7 lesson).
// ---------------------------------------------------------------------------
__global__ __launch_bounds__(256) void gemm_qkv(
    const float* __restrict__ X,
    const unsigned short* __restrict__ Wb,   // [3][1024][1024] bf16
    unsigned short* __restrict__ Yq, unsigned short* __restrict__ Yk, unsigned short* __restrict__ Yv)
{
    __shared__ __align__(16) unsigned char pool[36864];
    unsigned short* As = (unsigned short*)pool;        // 128 x 72
    unsigned short* Bs = As + 128 * 72;                // 128 x 72

    const int tid  = threadIdx.x;
    const int wave = tid >> 6;
    const int lane = tid & 63;
    const int c    = lane & 15;
    const int quad = lane >> 4;

    const int m0 = blockIdx.y * 128;
    const int n0 = blockIdx.x * 128;
    const int w_idx = n0 >> 10;
    const int e0    = n0 & 1023;
    const unsigned short* Wsrc = Wb + (size_t)w_idx * (DMODEL * DMODEL);

    const int mhalf = (wave & 1) * 64;
    const int nhalf = (wave >> 1) * 64;

    f32x4 acc[4][4];
#pragma unroll
    for (int i = 0; i < 4; i++)
#pragma unroll
        for (int j = 0; j < 4; j++) acc[i][j] = (f32x4){0.f, 0.f, 0.f, 0.f};

    const int srow = tid >> 3;        // 0..31
    const int scol = (tid & 7) * 8;   // 0..56 (elements)

    for (int k0 = 0; k0 < DMODEL; k0 += 64) {
        __syncthreads();
#pragma unroll
        for (int i = 0; i < 4; i++) {
            int row = i * 32 + srow;
            const float* p = X + (size_t)(m0 + row) * DMODEL + k0 + scol;
            float4 va = *(const float4*)(p);
            float4 vb = *(const float4*)(p + 4);
            u16x8 h;
            h[0] = f2bfu(va.x); h[1] = f2bfu(va.y); h[2] = f2bfu(va.z); h[3] = f2bfu(va.w);
            h[4] = f2bfu(vb.x); h[5] = f2bfu(vb.y); h[6] = f2bfu(vb.z); h[7] = f2bfu(vb.w);
            *(u16x8*)(&As[row * 72 + scol]) = h;
            *(u16x8*)(&Bs[row * 72 + scol]) =
                *(const u16x8*)(Wsrc + (size_t)(e0 + row) * DMODEL + k0 + scol);
        }
        __syncthreads();

#pragma unroll
        for (int half = 0; half < 2; half++) {
            bf16x8 af[4], bfr[4];
#pragma unroll
            for (int mt = 0; mt < 4; mt++)
                af[mt] = *(const bf16x8*)(&As[(mhalf + mt * 16 + c) * 72 + half * 32 + quad * 8]);
#pragma unroll
            for (int nt = 0; nt < 4; nt++)
                bfr[nt] = *(const bf16x8*)(&Bs[(nhalf + nt * 16 + c) * 72 + half * 32 + quad * 8]);
#pragma unroll
            for (int mt = 0; mt < 4; mt++)
#pragma unroll
                for (int nt = 0; nt < 4; nt++)
                    acc[mt][nt] = __builtin_amdgcn_mfma_f32_16x16x32_bf16(af[mt], bfr[nt], acc[mt][nt], 0, 0, 0);
        }
    }

    __syncthreads();   // staging dead; pool becomes epilogue space

    const int h = (e0 + nhalf) >> 6;
    if (w_idx < 2) {
        // Q/K: fp32 slab -> LDS -> row-major readback + in-lane RoPE
        unsigned short* Yqk = (w_idx == 0) ? Yq : Yk;
        float* EPf = (float*)pool + wave * 16 * 68;
        const int row = lane >> 2;
        const int cg  = lane & 3;
#pragma unroll
        for (int mt = 0; mt < 4; mt++) {
            LGKM0();
#pragma unroll
            for (int nt = 0; nt < 4; nt++)
#pragma unroll
                for (int r = 0; r < 4; r++)
                    EPf[(quad * 4 + r) * 68 + nt * 16 + c] = acc[mt][nt][r];
            LGKM0();
            float fl[16];
#pragma unroll
            for (int j = 0; j < 4; j++) {
                float4 v = *(const float4*)(&EPf[row * 68 + cg * 16 + j * 4]);
                fl[j * 4 + 0] = v.x; fl[j * 4 + 1] = v.y;
                fl[j * 4 + 2] = v.z; fl[j * 4 + 3] = v.w;
            }
            int m = m0 + mhalf + mt * 16 + row;
            int s = m & (S_LEN - 1);
            int b = m >> 11;
            u16x8 o0, o1;
#pragma unroll
            for (int pi = 0; pi < 8; pi++) {
                int p = cg * 8 + pi;
                float freq  = exp2f(-(float)p * 0.41524101186092034f);
                float angle = (float)s * freq;
                float sn, cs;
                __sincosf(angle, &sn, &cs);
                float ev = fl[2 * pi], ov = fl[2 * pi + 1];
                float re = ev * cs - ov * sn;
                float ro = ev * sn + ov * cs;
                if (pi < 4) { o0[2 * pi] = f2bfu(re); o0[2 * pi + 1] = f2bfu(ro); }
                else        { o1[2 * (pi - 4)] = f2bfu(re); o1[2 * (pi - 4) + 1] = f2bfu(ro); }
            }
            unsigned short* dst = Yqk + (((size_t)(b * NHEADS + h)) * S_LEN + s) * DKH + cg * 16;
            *(u16x8*)(dst)     = o0;
            *(u16x8*)(dst + 8) = o1;
        }
    } else {
        // V: bf16 transposed tile in LDS; lane = dk writes full 128B lines
        unsigned short* EPb = (unsigned short*)pool + wave * 64 * 72;
        LGKM0();
#pragma unroll
        for (int nt = 0; nt < 4; nt++)
#pragma unroll
            for (int mt = 0; mt < 4; mt++)
#pragma unroll
                for (int r = 0; r < 4; r++)
                    EPb[(nt * 16 + c) * 72 + mt * 16 + quad * 4 + r] = f2bfu(acc[mt][nt][r]);
        LGKM0();
        int mbase = m0 + mhalf;
        int s0 = mbase & (S_LEN - 1);
        int b  = mbase >> 11;
        unsigned short* dst = Yv + (((size_t)(b * NHEADS + h)) * DKH + lane) * S_LEN + s0;
#pragma unroll
        for (int j = 0; j < 8; j++)
            *(u16x8*)(dst + j * 8) = *(const u16x8*)(&EPb[lane * 72 + j * 8]);
    }
}

// ---------------------------------------------------------------------------
// Wo MFMA GEMM R12: 64x128 tile (512 blocks, R10 win), BK=64 (32->16 iters,
// 16 MFMA/iter), loads inside staging phase (no reg prefetch).
// ---------------------------------------------------------------------------
__global__ __launch_bounds__(256) void gemm_wo(
    const unsigned short* __restrict__ X,   // bf16 A, (MROWS x DMODEL)
    const float* __restrict__ W,            // fp32 Wo
    float* __restrict__ Yf)                 // fp32 out
{
    __shared__ __align__(16) unsigned char pool[27648];
    unsigned short* As = (unsigned short*)pool;        // 64 x 72
    unsigned short* Bs = As + 64 * 72;                 // 128 x 72

    const int tid  = threadIdx.x;
    const int wave = tid >> 6;
    const int lane = tid & 63;
    const int c    = lane & 15;
    const int quad = lane >> 4;

    const int m0 = blockIdx.y * 64;
    const int n0 = blockIdx.x * 128;

    const int mhalf = (wave & 1) * 32;
    const int nhalf = (wave >> 1) * 64;

    f32x4 acc[2][4];
#pragma unroll
    for (int i = 0; i < 2; i++)
#pragma unroll
        for (int j = 0; j < 4; j++) acc[i][j] = (f32x4){0.f, 0.f, 0.f, 0.f};

    const int srow = tid >> 3;        // 0..31
    const int scol = (tid & 7) * 8;

    for (int k0 = 0; k0 < DMODEL; k0 += 64) {
        __syncthreads();
#pragma unroll
        for (int i = 0; i < 2; i++) {
            int row = i * 32 + srow;
            *(u16x8*)(&As[row * 72 + scol]) =
                *(const u16x8*)(X + (size_t)(m0 + row) * DMODEL + k0 + scol);
        }
#pragma unroll
        for (int i = 0; i < 4; i++) {
            int row = i * 32 + srow;
            const float* p = W + (size_t)(n0 + row) * DMODEL + k0 + scol;
            float4 va = *(const float4*)(p);
            float4 vb = *(const float4*)(p + 4);
            u16x8 h;
            h[0] = f2bfu(va.x); h[1] = f2bfu(va.y); h[2] = f2bfu(va.z); h[3] = f2bfu(va.w);
            h[4] = f2bfu(vb.x); h[5] = f2bfu(vb.y); h[6] = f2bfu(vb.z); h[7] = f2bfu(vb.w);
            *(u16x8*)(&Bs[row * 72 + scol]) = h;
        }
        __syncthreads();

#pragma unroll
        for (int half = 0; half < 2; half++) {
            bf16x8 af[2], bfr[4];
#pragma unroll
            for (int mt = 0; mt < 2; mt++)
                af[mt] = *(const bf16x8*)(&As[(mhalf + mt * 16 + c) * 72 + half * 32 + quad * 8]);
#pragma unroll
            for (int nt = 0; nt < 4; nt++)
                bfr[nt] = *(const bf16x8*)(&Bs[(nhalf + nt * 16 + c) * 72 + half * 32 + quad * 8]);
#pragma unroll
            for (int mt = 0; mt < 2; mt++)
#pragma unroll
                for (int nt = 0; nt < 4; nt++)
                    acc[mt][nt] = __builtin_amdgcn_mfma_f32_16x16x32_bf16(af[mt], bfr[nt], acc[mt][nt], 0, 0, 0);
        }
    }

    __syncthreads();

    float* EPf = (float*)pool + wave * 16 * 68;
    const int row = lane >> 2;
    const int cg  = lane & 3;
#pragma unroll
    for (int mt = 0; mt < 2; mt++) {
        LGKM0();
#pragma unroll
        for (int nt = 0; nt < 4; nt++)
#pragma unroll
            for (int r = 0; r < 4; r++)
                EPf[(quad * 4 + r) * 68 + nt * 16 + c] = acc[mt][nt][r];
        LGKM0();
        int m = m0 + mhalf + mt * 16 + row;
        float* dst = Yf + (size_t)m * DMODEL + n0 + nhalf + cg * 16;
#pragma unroll
        for (int j = 0; j < 4; j++)
            *(float4*)(dst + j * 4) = *(const float4*)(&EPf[row * 68 + cg * 16 + j * 4]);
    }
}

// ---------------------------------------------------------------------------
// MFMA flash attention (unchanged from R11): BK=64, causal, no-max softmax,
// LPT dispatch, LDS K/V staging with reg prefetch, mask-free fast path.
// ---------------------------------------------------------------------------
__global__ __launch_bounds__(256, 4) void attn_mfma(
    const unsigned short* __restrict__ Q,   // [b,h,s,dk] bf16
    const unsigned short* __restrict__ K,   // [b,h,s,dk] bf16
    const unsigned short* __restrict__ Vt,  // [b,h,dk,s] bf16 (transposed)
    unsigned short* __restrict__ A)         // [b,s,h*dk] bf16
{
    __shared__ unsigned short Ks[64 * 72];
    __shared__ unsigned short Vs[64 * 72];
    __shared__ unsigned short Plds[4][16 * 72];

    const int tid  = threadIdx.x;
    const int wave = tid >> 6;
    const int lane = tid & 63;
    const int c    = lane & 15;
    const int quad = lane >> 4;

    const int bh = blockIdx.x;
    const int b  = bh >> 4;
    const int h  = bh & 15;
    const int qb = (int)(gridDim.y - 1) - (int)blockIdx.y;   // heavy-first
    const int q0 = qb * 64 + wave * 16;

    const unsigned short* Qb = Q  + (size_t)bh * S_LEN * DKH;
    const unsigned short* Kb = K  + (size_t)bh * S_LEN * DKH;
    const unsigned short* Vb = Vt + (size_t)bh * DKH * S_LEN;

    bf16x8 qf0 = *(const bf16x8*)(Qb + (q0 + c) * DKH + quad * 8);
    bf16x8 qf1 = *(const bf16x8*)(Qb + (q0 + c) * DKH + 32 + quad * 8);

    f32x4 o[4];
#pragma unroll
    for (int dt = 0; dt < 4; dt++) o[dt] = (f32x4){0.f,0.f,0.f,0.f};
    float l[4] = {0.f, 0.f, 0.f, 0.f};

    unsigned short* Pw = &Plds[wave][0];

    const int nkb     = qb + 1;
    const int kb_full = (q0 >= 63) ? (((q0 - 63) >> 6) + 1) : 0;

    const int srow = tid >> 2;
    const int scol = (tid & 3) * 16;

    uint4 gK0 = *(const uint4*)(Kb + (size_t)srow * DKH + scol);
    uint4 gK1 = *(const uint4*)(Kb + (size_t)srow * DKH + scol + 8);
    uint4 gV0 = *(const uint4*)(Vb + (size_t)srow * S_LEN + scol);
    uint4 gV1 = *(const uint4*)(Vb + (size_t)srow * S_LEN + scol + 8);

    for (int kb = 0; kb < nkb; kb++) {
        const int k0 = kb * 64;
        __syncthreads();
        *(uint4*)(&Ks[srow * 72 + scol])     = gK0;
        *(uint4*)(&Ks[srow * 72 + scol + 8]) = gK1;
        *(uint4*)(&Vs[srow * 72 + scol])     = gV0;
        *(uint4*)(&Vs[srow * 72 + scol + 8]) = gV1;
        __syncthreads();
        if (kb + 1 < nkb) {
            gK0 = *(const uint4*)(Kb + (size_t)(k0 + 64 + srow) * DKH + scol);
            gK1 = *(const uint4*)(Kb + (size_t)(k0 + 64 + srow) * DKH + scol + 8);
            gV0 = *(const uint4*)(Vb + (size_t)srow * S_LEN + k0 + 64 + scol);
            gV1 = *(const uint4*)(Vb + (size_t)srow * S_LEN + k0 + 64 + scol + 8);
        }

        f32x4 s[4];
#pragma unroll
        for (int t = 0; t < 4; t++) {
            bf16x8 kA = *(const bf16x8*)(&Ks[(t * 16 + c) * 72 + quad * 8]);
            bf16x8 kB = *(const bf16x8*)(&Ks[(t * 16 + c) * 72 + 32 + quad * 8]);
            f32x4 z = {0.f,0.f,0.f,0.f};
            z = __builtin_amdgcn_mfma_f32_16x16x32_bf16(qf0, kA, z, 0, 0, 0);
            z = __builtin_amdgcn_mfma_f32_16x16x32_bf16(qf1, kB, z, 0, 0, 0);
            s[t] = z;
        }

        if (kb < kb_full) {
#pragma unroll
            for (int t = 0; t < 4; t++)
#pragma unroll
                for (int r = 0; r < 4; r++) {
                    unsigned short pb = f2bfu(__expf(s[t][r] * 0.125f));
                    Pw[(quad * 4 + r) * 72 + t * 16 + c] = pb;
                    l[r] += bfu2f(pb);
                }
        } else {
#pragma unroll
            for (int t = 0; t < 4; t++)
#pragma unroll
                for (int r = 0; r < 4; r++) {
                    int qrow = q0 + quad * 4 + r;
                    float e = (k0 + t * 16 + c <= qrow) ? __expf(s[t][r] * 0.125f) : 0.0f;
                    unsigned short pb = f2bfu(e);
                    Pw[(quad * 4 + r) * 72 + t * 16 + c] = pb;
                    l[r] += bfu2f(pb);
                }
        }
        LGKM0();

        bf16x8 pf0 = *(const bf16x8*)(Pw + c * 72 + quad * 8);
        bf16x8 pf1 = *(const bf16x8*)(Pw + c * 72 + 32 + quad * 8);

#pragma unroll
        for (int dt = 0; dt < 4; dt++) {
            bf16x8 vA = *(const bf16x8*)(&Vs[(dt * 16 + c) * 72 + quad * 8]);
            bf16x8 vB = *(const bf16x8*)(&Vs[(dt * 16 + c) * 72 + 32 + quad * 8]);
            o[dt] = __builtin_amdgcn_mfma_f32_16x16x32_bf16(pf0, vA, o[dt], 0, 0, 0);
            o[dt] = __builtin_amdgcn_mfma_f32_16x16x32_bf16(pf1, vB, o[dt], 0, 0, 0);
        }
    }

#pragma unroll
    for (int m = 1; m < 16; m <<= 1) {
#pragma unroll
        for (int r = 0; r < 4; r++) l[r] += __shfl_xor(l[r], m, 64);
    }

#pragma unroll
    for (int r = 0; r < 4; r++) {
        float inv = 1.0f / l[r];
        int s = q0 + quad * 4 + r;
        unsigned short* Ap = A + ((size_t)b * S_LEN + s) * DMODEL + h * DKH;
        Ap[0 * 16 + c] = f2bfu(o[0][r] * inv);
        Ap[1 * 16 + c] = f2bfu(o[1][r] * inv);
        Ap[2 * 16 + c] = f2bfu(o[2][r] * inv);
        Ap[3 * 16 + c] = f2bfu(o[3][r] * inv);
    }
}

extern "C" void kernel_launch(void* const* d_in, const int* in_sizes, int n_in,
                              void* d_out, int out_size, void* d_ws, size_t ws_size,
                              hipStream_t stream) {
    const float* x  = (const float*)d_in[0];
    const float* Wq = (const float*)d_in[1];
    const float* Wk = (const float*)d_in[2];
    const float* Wv = (const float*)d_in[3];
    const float* Wo = (const float*)d_in[4];
    float* out = (float*)d_out;

    // Workspace (exactly 32 MiB -- proven safe):
    //  [0,8)   Q bf16 [b,h,s,dk]
    //  [8,16)  K bf16 [b,h,s,dk]
    //  [16,24) V^T bf16 [b,h,dk,s]
    //  [24,32) phase A: Wqkv bf16 (cvt_w -> gemm_qkv); phase B: A (attn -> gemm_wo)
    unsigned short* Qw = (unsigned short*)d_ws;
    unsigned short* Kw = Qw + (size_t)MROWS * DMODEL;
    unsigned short* Vw = Kw + (size_t)MROWS * DMODEL;
    unsigned short* Wb = Vw + (size_t)MROWS * DMODEL;   // 3 MB*2 = 6 MB used
    unsigned short* Aw = Wb;                            // aliased; QKV done before attn

    cvt_w<<<dim3(DMODEL * DMODEL / (256 * 8), 3), 256, 0, stream>>>(Wq, Wk, Wv, Wb);

    gemm_qkv<<<dim3(3 * DMODEL / 128, MROWS / 128), 256, 0, stream>>>(
        x, Wb, Qw, Kw, Vw);

    attn_mfma<<<dim3(NHEADS * BATCH, S_LEN / 64), 256, 0, stream>>>(Qw, Kw, Vw, Aw);

    gemm_wo<<<dim3(DMODEL / 128, MROWS / 64), 256, 0, stream>>>(Aw, Wo, out);
}

// Round 13
// 193.943 us; speedup vs baseline: 1.0360x; 1.0360x over previous
//
#include <hip/hip_runtime.h>
#include <hip/hip_bf16.h>
#include <math.h>

// Problem constants
#define S_LEN   2048
#define BATCH   2
#define DMODEL  1024
#define NHEADS  16
#define DKH     64
#define MROWS   (BATCH * S_LEN)   // 4096

typedef __attribute__((ext_vector_type(8))) __bf16 bf16x8;
typedef __attribute__((ext_vector_type(4))) float f32x4;
typedef __attribute__((ext_vector_type(8))) unsigned short u16x8;

__device__ __forceinline__ float bfu2f(unsigned short u) {
    union { unsigned int i; float f; } v;
    v.i = ((unsigned int)u) << 16;
    return v.f;
}

__device__ __forceinline__ unsigned short f2bfu(float f) {
    union { __bf16 h; unsigned short u; } v;
    v.h = (__bf16)f;    // native RNE cvt
    return v.u;
}

#define LGKM0() __builtin_amdgcn_s_waitcnt(0xc07f)   // lgkmcnt(0), vmcnt free

#define SROW 40   // staging LDS row stride in halves (80 B, 16B-aligned)

// ---------------------------------------------------------------------------
// Weight pre-convert: Wq/Wk/Wv fp32 -> bf16 into ws[24MB..30MB). Region later
// overwritten by A (attn output) -- safe, QKV completes first (stream order).
// ---------------------------------------------------------------------------
__global__ __launch_bounds__(256) void cvt_w(
    const float* __restrict__ W0, const float* __restrict__ W1, const float* __restrict__ W2,
    unsigned short* __restrict__ Wb)   // [3][1024*1024] bf16
{
    const float* W = (blockIdx.y == 0) ? W0 : (blockIdx.y == 1) ? W1 : W2;
    size_t idx = ((size_t)blockIdx.x * 256 + threadIdx.x) * 8;
    float4 a = *(const float4*)(W + idx);
    float4 b = *(const float4*)(W + idx + 4);
    u16x8 h;
    h[0] = f2bfu(a.x); h[1] = f2bfu(a.y); h[2] = f2bfu(a.z); h[3] = f2bfu(a.w);
    h[4] = f2bfu(b.x); h[5] = f2bfu(b.y); h[6] = f2bfu(b.z); h[7] = f2bfu(b.w);
    *(u16x8*)(Wb + (size_t)blockIdx.y * (DMODEL * DMODEL) + idx) = h;
}

// ---------------------------------------------------------------------------
// QKV MFMA GEMM R13: the measured-best R9 structure (BK=32, 76 VGPR, 61us) with
// ONE change: B operand is pre-converted bf16, so B staging is a pure 16B copy
// (2 u16x8 per thread) instead of 4 float4 loads + 8 packed cvts.
// R12 lesson: BK=64 bloats VGPR (100) and kills occupancy -- stay at BK=32.
// R10 lesson: no cross-phase register prefetch.
// Epilogues: LDS round-trip, full-line stores (R7 lesson).
// ---------------------------------------------------------------------------
__global__ __launch_bounds__(256) void gemm_qkv(
    const float* __restrict__ X,
    const unsigned short* __restrict__ Wb,   // [3][1024][1024] bf16
    unsigned short* __restrict__ Yq, unsigned short* __restrict__ Yk, unsigned short* __restrict__ Yv)
{
    __shared__ __align__(16) unsigned char pool[36864];
    unsigned short* As = (unsigned short*)pool;        // 128 x SROW
    unsigned short* Bs = As + 128 * SROW;              // 128 x SROW

    const int tid  = threadIdx.x;
    const int wave = tid >> 6;
    const int lane = tid & 63;
    const int c    = lane & 15;
    const int quad = lane >> 4;

    const int m0 = blockIdx.y * 128;
    const int n0 = blockIdx.x * 128;
    const int w_idx = n0 >> 10;
    const int e0    = n0 & 1023;
    const unsigned short* Wsrc = Wb + (size_t)w_idx * (DMODEL * DMODEL);

    const int mhalf = (wave & 1) * 64;
    const int nhalf = (wave >> 1) * 64;

    f32x4 acc[4][4];
#pragma unroll
    for (int i = 0; i < 4; i++)
#pragma unroll
        for (int j = 0; j < 4; j++) acc[i][j] = (f32x4){0.f, 0.f, 0.f, 0.f};

    const int lrow = tid >> 3;        // 0..31
    const int lkq  = tid & 7;         // 0..7  (x4 floats)
    const int brow = tid >> 2;        // 0..63
    const int bchk = (tid & 3) * 8;   // 0,8,16,24 halves

    for (int k0 = 0; k0 < DMODEL; k0 += 32) {
        __syncthreads();
        // A tile: fp32 x -> bf16 cvt (128 x 32)
#pragma unroll
        for (int i = 0; i < 4; i++) {
            int row = i * 32 + lrow;
            float4 v = *(const float4*)(X + (size_t)(m0 + row) * DMODEL + k0 + lkq * 4);
            ushort4 h;
            h.x = f2bfu(v.x); h.y = f2bfu(v.y); h.z = f2bfu(v.z); h.w = f2bfu(v.w);
            *(ushort4*)(&As[row * SROW + lkq * 4]) = h;
        }
        // B tile: pure bf16 copy (128 x 32)
#pragma unroll
        for (int i = 0; i < 2; i++) {
            int row = i * 64 + brow;
            *(u16x8*)(&Bs[row * SROW + bchk]) =
                *(const u16x8*)(Wsrc + (size_t)(e0 + row) * DMODEL + k0 + bchk);
        }
        __syncthreads();

        bf16x8 af[4], bfr[4];
#pragma unroll
        for (int mt = 0; mt < 4; mt++)
            af[mt] = *(const bf16x8*)(&As[(mhalf + mt * 16 + c) * SROW + quad * 8]);
#pragma unroll
        for (int nt = 0; nt < 4; nt++)
            bfr[nt] = *(const bf16x8*)(&Bs[(nhalf + nt * 16 + c) * SROW + quad * 8]);
#pragma unroll
        for (int mt = 0; mt < 4; mt++)
#pragma unroll
            for (int nt = 0; nt < 4; nt++)
                acc[mt][nt] = __builtin_amdgcn_mfma_f32_16x16x32_bf16(af[mt], bfr[nt], acc[mt][nt], 0, 0, 0);
    }

    __syncthreads();   // staging dead; pool becomes epilogue space

    const int h = (e0 + nhalf) >> 6;
    if (w_idx < 2) {
        // Q/K: fp32 slab -> LDS -> row-major readback + in-lane RoPE
        unsigned short* Yqk = (w_idx == 0) ? Yq : Yk;
        float* EPf = (float*)pool + wave * 16 * 68;
        const int row = lane >> 2;
        const int cg  = lane & 3;
#pragma unroll
        for (int mt = 0; mt < 4; mt++) {
            LGKM0();
#pragma unroll
            for (int nt = 0; nt < 4; nt++)
#pragma unroll
                for (int r = 0; r < 4; r++)
                    EPf[(quad * 4 + r) * 68 + nt * 16 + c] = acc[mt][nt][r];
            LGKM0();
            float fl[16];
#pragma unroll
            for (int j = 0; j < 4; j++) {
                float4 v = *(const float4*)(&EPf[row * 68 + cg * 16 + j * 4]);
                fl[j * 4 + 0] = v.x; fl[j * 4 + 1] = v.y;
                fl[j * 4 + 2] = v.z; fl[j * 4 + 3] = v.w;
            }
            int m = m0 + mhalf + mt * 16 + row;
            int s = m & (S_LEN - 1);
            int b = m >> 11;
            u16x8 o0, o1;
#pragma unroll
            for (int pi = 0; pi < 8; pi++) {
                int p = cg * 8 + pi;
                float freq  = exp2f(-(float)p * 0.41524101186092034f);
                float angle = (float)s * freq;
                float sn, cs;
                __sincosf(angle, &sn, &cs);
                float ev = fl[2 * pi], ov = fl[2 * pi + 1];
                float re = ev * cs - ov * sn;
                float ro = ev * sn + ov * cs;
                if (pi < 4) { o0[2 * pi] = f2bfu(re); o0[2 * pi + 1] = f2bfu(ro); }
                else        { o1[2 * (pi - 4)] = f2bfu(re); o1[2 * (pi - 4) + 1] = f2bfu(ro); }
            }
            unsigned short* dst = Yqk + (((size_t)(b * NHEADS + h)) * S_LEN + s) * DKH + cg * 16;
            *(u16x8*)(dst)     = o0;
            *(u16x8*)(dst + 8) = o1;
        }
    } else {
        // V: bf16 transposed tile in LDS; lane = dk writes full 128B lines
        unsigned short* EPb = (unsigned short*)pool + wave * 64 * 72;
        LGKM0();
#pragma unroll
        for (int nt = 0; nt < 4; nt++)
#pragma unroll
            for (int mt = 0; mt < 4; mt++)
#pragma unroll
                for (int r = 0; r < 4; r++)
                    EPb[(nt * 16 + c) * 72 + mt * 16 + quad * 4 + r] = f2bfu(acc[mt][nt][r]);
        LGKM0();
        int mbase = m0 + mhalf;
        int s0 = mbase & (S_LEN - 1);
        int b  = mbase >> 11;
        unsigned short* dst = Yv + (((size_t)(b * NHEADS + h)) * DKH + lane) * S_LEN + s0;
#pragma unroll
        for (int j = 0; j < 8; j++)
            *(u16x8*)(dst + j * 8) = *(const u16x8*)(&EPb[lane * 72 + j * 8]);
    }
}

// ---------------------------------------------------------------------------
// Wo MFMA GEMM — unchanged from R12 (its measured-best state): 64x128 tile,
// 512 blocks, BK=64 (fine here: 2x4 accum keeps VGPR low), no reg prefetch.
// ---------------------------------------------------------------------------
__global__ __launch_bounds__(256) void gemm_wo(
    const unsigned short* __restrict__ X,   // bf16 A, (MROWS x DMODEL)
    const float* __restrict__ W,            // fp32 Wo
    float* __restrict__ Yf)                 // fp32 out
{
    __shared__ __align__(16) unsigned char pool[27648];
    unsigned short* As = (unsigned short*)pool;        // 64 x 72
    unsigned short* Bs = As + 64 * 72;                 // 128 x 72

    const int tid  = threadIdx.x;
    const int wave = tid >> 6;
    const int lane = tid & 63;
    const int c    = lane & 15;
    const int quad = lane >> 4;

    const int m0 = blockIdx.y * 64;
    const int n0 = blockIdx.x * 128;

    const int mhalf = (wave & 1) * 32;
    const int nhalf = (wave >> 1) * 64;

    f32x4 acc[2][4];
#pragma unroll
    for (int i = 0; i < 2; i++)
#pragma unroll
        for (int j = 0; j < 4; j++) acc[i][j] = (f32x4){0.f, 0.f, 0.f, 0.f};

    const int srow = tid >> 3;        // 0..31
    const int scol = (tid & 7) * 8;

    for (int k0 = 0; k0 < DMODEL; k0 += 64) {
        __syncthreads();
#pragma unroll
        for (int i = 0; i < 2; i++) {
            int row = i * 32 + srow;
            *(u16x8*)(&As[row * 72 + scol]) =
                *(const u16x8*)(X + (size_t)(m0 + row) * DMODEL + k0 + scol);
        }
#pragma unroll
        for (int i = 0; i < 4; i++) {
            int row = i * 32 + srow;
            const float* p = W + (size_t)(n0 + row) * DMODEL + k0 + scol;
            float4 va = *(const float4*)(p);
            float4 vb = *(const float4*)(p + 4);
            u16x8 h;
            h[0] = f2bfu(va.x); h[1] = f2bfu(va.y); h[2] = f2bfu(va.z); h[3] = f2bfu(va.w);
            h[4] = f2bfu(vb.x); h[5] = f2bfu(vb.y); h[6] = f2bfu(vb.z); h[7] = f2bfu(vb.w);
            *(u16x8*)(&Bs[row * 72 + scol]) = h;
        }
        __syncthreads();

#pragma unroll
        for (int half = 0; half < 2; half++) {
            bf16x8 af[2], bfr[4];
#pragma unroll
            for (int mt = 0; mt < 2; mt++)
                af[mt] = *(const bf16x8*)(&As[(mhalf + mt * 16 + c) * 72 + half * 32 + quad * 8]);
#pragma unroll
            for (int nt = 0; nt < 4; nt++)
                bfr[nt] = *(const bf16x8*)(&Bs[(nhalf + nt * 16 + c) * 72 + half * 32 + quad * 8]);
#pragma unroll
            for (int mt = 0; mt < 2; mt++)
#pragma unroll
                for (int nt = 0; nt < 4; nt++)
                    acc[mt][nt] = __builtin_amdgcn_mfma_f32_16x16x32_bf16(af[mt], bfr[nt], acc[mt][nt], 0, 0, 0);
        }
    }

    __syncthreads();

    float* EPf = (float*)pool + wave * 16 * 68;
    const int row = lane >> 2;
    const int cg  = lane & 3;
#pragma unroll
    for (int mt = 0; mt < 2; mt++) {
        LGKM0();
#pragma unroll
        for (int nt = 0; nt < 4; nt++)
#pragma unroll
            for (int r = 0; r < 4; r++)
                EPf[(quad * 4 + r) * 68 + nt * 16 + c] = acc[mt][nt][r];
        LGKM0();
        int m = m0 + mhalf + mt * 16 + row;
        float* dst = Yf + (size_t)m * DMODEL + n0 + nhalf + cg * 16;
#pragma unroll
        for (int j = 0; j < 4; j++)
            *(float4*)(dst + j * 4) = *(const float4*)(&EPf[row * 68 + cg * 16 + j * 4]);
    }
}

// ---------------------------------------------------------------------------
// MFMA flash attention — exact R9/R10 BK=32 version (measured best ~53us;
// R11's BK=64 variant cost ~5us). Causal, no-max softmax, LPT dispatch,
// block-shared K/V LDS tiles with reg prefetch, mask-free fast path.
// ---------------------------------------------------------------------------
__global__ __launch_bounds__(256, 4) void attn_mfma(
    const unsigned short* __restrict__ Q,
    const unsigned short* __restrict__ K,
    const unsigned short* __restrict__ Vt,
    unsigned short* __restrict__ A)
{
    __shared__ unsigned short Ks[32 * 72];
    __shared__ unsigned short Vs[64 * 40];
    __shared__ unsigned short Plds[4][16 * 40];

    const int tid  = threadIdx.x;
    const int wave = tid >> 6;
    const int lane = tid & 63;
    const int c    = lane & 15;
    const int quad = lane >> 4;

    const int bh = blockIdx.x;
    const int b  = bh >> 4;
    const int h  = bh & 15;
    const int qb = (int)(gridDim.y - 1) - (int)blockIdx.y;
    const int q0b = qb * 64;
    const int q0 = q0b + wave * 16;

    const unsigned short* Qb = Q  + (size_t)bh * S_LEN * DKH;
    const unsigned short* Kb = K  + (size_t)bh * S_LEN * DKH;
    const unsigned short* Vb = Vt + (size_t)bh * DKH * S_LEN;

    bf16x8 qf0 = *(const bf16x8*)(Qb + (q0 + c) * DKH + quad * 8);
    bf16x8 qf1 = *(const bf16x8*)(Qb + (q0 + c) * DKH + 32 + quad * 8);

    f32x4 o0 = {0.f,0.f,0.f,0.f}, o1 = o0, o2 = o0, o3 = o0;
    float l[4] = {0.f, 0.f, 0.f, 0.f};

    unsigned short* Pw = &Plds[wave][0];

    const int my_nkb   = (q0 + 16 + 31) >> 5;
    const int nkb_blk  = (q0b + 64 + 31) >> 5;
    const int kb_full  = (q0 >= 31) ? (((q0 - 31) >> 5) + 1) : 0;

    const int krow  = tid >> 3;
    const int kcol8 = (tid & 7) * 8;
    const int vrow  = tid >> 2;
    const int vcol8 = (tid & 3) * 8;

    uint4 gK = *(const uint4*)(Kb + (size_t)krow * DKH + kcol8);
    uint4 gV = *(const uint4*)(Vb + (size_t)vrow * S_LEN + vcol8);

    for (int kb = 0; kb < nkb_blk; kb++) {
        const int k0 = kb * 32;
        __syncthreads();
        *(uint4*)(&Ks[krow * 72 + kcol8]) = gK;
        *(uint4*)(&Vs[vrow * 40 + vcol8]) = gV;
        __syncthreads();
        if (kb + 1 < nkb_blk) {
            gK = *(const uint4*)(Kb + (size_t)(k0 + 32 + krow) * DKH + kcol8);
            gV = *(const uint4*)(Vb + (size_t)vrow * S_LEN + k0 + 32 + vcol8);
        }
        if (kb < my_nkb) {
            bf16x8 k00 = *(const bf16x8*)(&Ks[c * 72 + quad * 8]);
            bf16x8 k01 = *(const bf16x8*)(&Ks[c * 72 + 32 + quad * 8]);
            bf16x8 k10 = *(const bf16x8*)(&Ks[(16 + c) * 72 + quad * 8]);
            bf16x8 k11 = *(const bf16x8*)(&Ks[(16 + c) * 72 + 32 + quad * 8]);
            f32x4 s0 = {0.f,0.f,0.f,0.f}, s1 = {0.f,0.f,0.f,0.f};
            s0 = __builtin_amdgcn_mfma_f32_16x16x32_bf16(qf0, k00, s0, 0, 0, 0);
            s0 = __builtin_amdgcn_mfma_f32_16x16x32_bf16(qf1, k01, s0, 0, 0, 0);
            s1 = __builtin_amdgcn_mfma_f32_16x16x32_bf16(qf0, k10, s1, 0, 0, 0);
            s1 = __builtin_amdgcn_mfma_f32_16x16x32_bf16(qf1, k11, s1, 0, 0, 0);

            if (kb < kb_full) {
#pragma unroll
                for (int r = 0; r < 4; r++) {
                    float e0 = __expf(s0[r] * 0.125f);
                    float e1 = __expf(s1[r] * 0.125f);
                    unsigned short pb0 = f2bfu(e0);
                    unsigned short pb1 = f2bfu(e1);
                    Pw[(quad * 4 + r) * 40 + c]      = pb0;
                    Pw[(quad * 4 + r) * 40 + 16 + c] = pb1;
                    l[r] += bfu2f(pb0) + bfu2f(pb1);
                }
            } else {
#pragma unroll
                for (int r = 0; r < 4; r++) {
                    int qrow = q0 + quad * 4 + r;
                    float e0 = (k0 + c      <= qrow) ? __expf(s0[r] * 0.125f) : 0.0f;
                    float e1 = (k0 + 16 + c <= qrow) ? __expf(s1[r] * 0.125f) : 0.0f;
                    unsigned short pb0 = f2bfu(e0);
                    unsigned short pb1 = f2bfu(e1);
                    Pw[(quad * 4 + r) * 40 + c]      = pb0;
                    Pw[(quad * 4 + r) * 40 + 16 + c] = pb1;
                    l[r] += bfu2f(pb0) + bfu2f(pb1);
                }
            }
            LGKM0();

            bf16x8 pf = *(const bf16x8*)(Pw + c * 40 + quad * 8);

            bf16x8 vf0 = *(const bf16x8*)(&Vs[(0 * 16 + c) * 40 + quad * 8]);
            bf16x8 vf1 = *(const bf16x8*)(&Vs[(1 * 16 + c) * 40 + quad * 8]);
            bf16x8 vf2 = *(const bf16x8*)(&Vs[(2 * 16 + c) * 40 + quad * 8]);
            bf16x8 vf3 = *(const bf16x8*)(&Vs[(3 * 16 + c) * 40 + quad * 8]);
            o0 = __builtin_amdgcn_mfma_f32_16x16x32_bf16(pf, vf0, o0, 0, 0, 0);
            o1 = __builtin_amdgcn_mfma_f32_16x16x32_bf16(pf, vf1, o1, 0, 0, 0);
            o2 = __builtin_amdgcn_mfma_f32_16x16x32_bf16(pf, vf2, o2, 0, 0, 0);
            o3 = __builtin_amdgcn_mfma_f32_16x16x32_bf16(pf, vf3, o3, 0, 0, 0);
        }
    }

#pragma unroll
    for (int m = 1; m < 16; m <<= 1) {
#pragma unroll
        for (int r = 0; r < 4; r++) l[r] += __shfl_xor(l[r], m, 64);
    }

#pragma unroll
    for (int r = 0; r < 4; r++) {
        float inv = 1.0f / l[r];
        int s = q0 + quad * 4 + r;
        unsigned short* Ap = A + ((size_t)b * S_LEN + s) * DMODEL + h * DKH;
        Ap[0 * 16 + c] = f2bfu(o0[r] * inv);
        Ap[1 * 16 + c] = f2bfu(o1[r] * inv);
        Ap[2 * 16 + c] = f2bfu(o2[r] * inv);
        Ap[3 * 16 + c] = f2bfu(o3[r] * inv);
    }
}

extern "C" void kernel_launch(void* const* d_in, const int* in_sizes, int n_in,
                              void* d_out, int out_size, void* d_ws, size_t ws_size,
                              hipStream_t stream) {
    const float* x  = (const float*)d_in[0];
    const float* Wq = (const float*)d_in[1];
    const float* Wk = (const float*)d_in[2];
    const float* Wv = (const float*)d_in[3];
    const float* Wo = (const float*)d_in[4];
    float* out = (float*)d_out;

    // Workspace (exactly 32 MiB -- proven safe):
    //  [0,8)   Q bf16 [b,h,s,dk]
    //  [8,16)  K bf16 [b,h,s,dk]
    //  [16,24) V^T bf16 [b,h,dk,s]
    //  [24,32) phase A: Wqkv bf16 (cvt_w -> gemm_qkv); phase B: A (attn -> gemm_wo)
    unsigned short* Qw = (unsigned short*)d_ws;
    unsigned short* Kw = Qw + (size_t)MROWS * DMODEL;
    unsigned short* Vw = Kw + (size_t)MROWS * DMODEL;
    unsigned short* Wb = Vw + (size_t)MROWS * DMODEL;
    unsigned short* Aw = Wb;   // aliased; QKV completes before attn writes A

    cvt_w<<<dim3(DMODEL * DMODEL / (256 * 8), 3), 256, 0, stream>>>(Wq, Wk, Wv, Wb);

    gemm_qkv<<<dim3(3 * DMODEL / 128, MROWS / 128), 256, 0, stream>>>(
        x, Wb, Qw, Kw, Vw);

    attn_mfma<<<dim3(NHEADS * BATCH, S_LEN / 64), 256, 0, stream>>>(Qw, Kw, Vw, Aw);

    gemm_wo<<<dim3(DMODEL / 128, MROWS / 64), 256, 0, stream>>>(Aw, Wo, out);
}